// Round 5
// baseline (1053.581 us; speedup 1.0000x reference)
//
#include <hip/hip_runtime.h>

#define N_NODES 100000
#define N_EDGES 1600000
#define IN_F 128
#define H_F 64
#define C_F 16

#define BIN_SH 9
#define BIN_NODES 512          // 1 << BIN_SH
#define NBINS 196              // ceil(100000 / 512)
#define PART_BLOCKS 192
#define CNT_BLOCKS 256

typedef __attribute__((ext_vector_type(8))) short bf16x8;  // 8 bf16 (4 VGPRs)
typedef __attribute__((ext_vector_type(4))) float f32x4;   // MFMA C/D

// fp32 -> bf16 round-to-nearest-even (finite inputs)
__device__ inline unsigned short f2bf(float f) {
  unsigned u = __float_as_uint(f);
  unsigned r = (u + 0x7fff + ((u >> 16) & 1)) >> 16;
  return (unsigned short)r;
}
__device__ inline float bf2f(unsigned short s) {
  return __uint_as_float(((unsigned)s) << 16);
}

// ---------------- GEMM1 (MFMA): H1b = bf16(X @ W1) ------------------------
// One wave = 16(node) x 64(feat) tile; B pre-swizzled in LDS (ds_read_b128).
__global__ __launch_bounds__(256) void gemm1_mfma_kernel(
    const float* __restrict__ X, const float* __restrict__ W1,
    unsigned short* __restrict__ H1b) {
  __shared__ short ldsB[16 * 512];  // 16 frags x (64 lanes x 8 bf16) = 16 KB
  for (int idx = threadIdx.x; idx < 16 * 512; idx += 256) {
    int frag = idx >> 9;    // c*4 + s
    int entry = idx & 511;  // lane*8 + j
    int lane = entry >> 3, j = entry & 7;
    int c = frag >> 2, s = frag & 3;
    int k = s * 32 + (lane >> 4) * 8 + j;
    int n = c * 16 + (lane & 15);
    ldsB[idx] = (short)f2bf(W1[k * H_F + n]);
  }
  __syncthreads();

  int wave = threadIdx.x >> 6;
  int lane = threadIdx.x & 63;
  int rt = blockIdx.x * 4 + wave;  // 16-node row tile
  if (rt >= N_NODES / 16) return;  // 6250 tiles exactly
  int node0 = rt * 16;
  int l = lane & 15, q = lane >> 4;

  const float* xp = X + (size_t)(node0 + l) * IN_F + q * 8;
  f32x4 acc[4] = {f32x4{0.f, 0.f, 0.f, 0.f}, f32x4{0.f, 0.f, 0.f, 0.f},
                  f32x4{0.f, 0.f, 0.f, 0.f}, f32x4{0.f, 0.f, 0.f, 0.f}};
#pragma unroll
  for (int s = 0; s < 4; ++s) {
    float4 x0 = *(const float4*)(xp + s * 32);
    float4 x1 = *(const float4*)(xp + s * 32 + 4);
    bf16x8 a;
    a[0] = f2bf(x0.x); a[1] = f2bf(x0.y); a[2] = f2bf(x0.z); a[3] = f2bf(x0.w);
    a[4] = f2bf(x1.x); a[5] = f2bf(x1.y); a[6] = f2bf(x1.z); a[7] = f2bf(x1.w);
#pragma unroll
    for (int c = 0; c < 4; ++c) {
      bf16x8 b = *(const bf16x8*)&ldsB[(c * 4 + s) * 512 + lane * 8];
      acc[c] = __builtin_amdgcn_mfma_f32_16x16x32_bf16(a, b, acc[c], 0, 0, 0);
    }
  }
  // C/D: col = lane&15 (feat), row = q*4 + reg (node)
#pragma unroll
  for (int c = 0; c < 4; ++c)
#pragma unroll
    for (int r = 0; r < 4; ++r)
      H1b[(size_t)(node0 + q * 4 + r) * H_F + c * 16 + l] = f2bf(acc[c][r]);
}

// ---------------- bin build: zero / count / scan / partition --------------
__global__ __launch_bounds__(256) void zero_bins_kernel(int* __restrict__ binCnt) {
  if (threadIdx.x < NBINS) binCnt[threadIdx.x] = 0;
}

__global__ __launch_bounds__(256) void bincount_kernel(
    const int* __restrict__ dst, int* __restrict__ binCnt) {
  __shared__ int h[NBINS];
  int tid = threadIdx.x;
  if (tid < NBINS) h[tid] = 0;
  __syncthreads();
  for (int e = blockIdx.x * 256 + tid; e < N_EDGES; e += CNT_BLOCKS * 256)
    atomicAdd(&h[dst[e] >> BIN_SH], 1);
  __syncthreads();
  if (tid < NBINS) atomicAdd(&binCnt[tid], h[tid]);
}

__global__ __launch_bounds__(256) void binscan_kernel(
    const int* __restrict__ binCnt, int* __restrict__ binOffs,
    int* __restrict__ binCursor) {
  __shared__ int s[256];
  int tid = threadIdx.x;
  int v = (tid < NBINS) ? binCnt[tid] : 0;
  s[tid] = v;
  __syncthreads();
#pragma unroll
  for (int d = 1; d < 256; d <<= 1) {
    int t = (tid >= d) ? s[tid - d] : 0;
    __syncthreads();
    s[tid] += t;
    __syncthreads();
  }
  if (tid < NBINS) {
    int ex = s[tid] - v;  // exclusive
    binOffs[tid] = ex;
    binCursor[tid] = ex;
  }
  if (tid == 0) binOffs[NBINS] = N_EDGES;
}

// Two-pass per-block partition: local hist -> one global reserve per
// (block,bin) -> placement via LDS cursors. ~38K global atomics total;
// stores land in per-(block,bin) contiguous runs (~340B) -> L2-merged.
// Record pack: x = src | (dst_local << 17)   (src<2^17, dst_local<512)
//              y = bits(edge_weight)
__global__ __launch_bounds__(256) void partition_kernel(
    const int* __restrict__ src, const int* __restrict__ dst,
    const float* __restrict__ ew, int* __restrict__ binCursor,
    int2* __restrict__ ebin) {
  __shared__ int hist[NBINS];
  __shared__ int cur[NBINS];
  int tid = threadIdx.x;
  if (tid < NBINS) hist[tid] = 0;
  __syncthreads();
  const int per = (N_EDGES + PART_BLOCKS - 1) / PART_BLOCKS;
  int lo = blockIdx.x * per;
  int hi = lo + per;
  if (hi > N_EDGES) hi = N_EDGES;
  for (int e = lo + tid; e < hi; e += 256) atomicAdd(&hist[dst[e] >> BIN_SH], 1);
  __syncthreads();
  if (tid < NBINS) cur[tid] = atomicAdd(&binCursor[tid], hist[tid]);
  __syncthreads();
  for (int e = lo + tid; e < hi; e += 256) {
    int d = dst[e];
    int b = d >> BIN_SH;
    int pos = atomicAdd(&cur[b], 1);
    ebin[pos] = make_int2(src[e] | ((d & (BIN_NODES - 1)) << 17),
                          __float_as_int(ew[e]));
  }
}

// ---------------- Gather1 (binned, LDS accumulate) ------------------------
// Block = (bin, 16-feat group). acc[512][16] = 32KB LDS, 4 blocks/CU.
// 16 lanes per edge (f = lane&15), 32 edge-slots x unroll 4 per block-iter.
__global__ __launch_bounds__(512) void gather1b_kernel(
    const unsigned short* __restrict__ H1b, const int* __restrict__ binOffs,
    const int2* __restrict__ ebin, const float* __restrict__ b1,
    float* __restrict__ agg) {
  __shared__ float acc[BIN_NODES * 16];
  int b = blockIdx.x >> 2;
  int g = blockIdx.x & 3;
  int tid = threadIdx.x;
  for (int i = tid; i < BIN_NODES * 16; i += 512) acc[i] = 0.f;
  __syncthreads();
  int off = binOffs[b], end = binOffs[b + 1];
  int sub = tid >> 4;  // 0..31
  int f = tid & 15;
  int gf = g * 16 + f;
  for (int ebase = off; ebase < end; ebase += 128) {
#pragma unroll
    for (int u = 0; u < 4; ++u) {
      int e = ebase + u * 32 + sub;
      int2 r = (e < end) ? ebin[e] : make_int2(0, 0);  // dummy: w=0, dl=0
      int srcn = r.x & 0x1FFFF;
      int dl = r.x >> 17;
      float w = __int_as_float(r.y);
      float v = bf2f(H1b[srcn * H_F + gf]) * w;
      atomicAdd(&acc[dl * 16 + f], v);
    }
  }
  __syncthreads();
  float bias = b1[gf];  // i&15 == f for stride-512 loop
  int nb = b << BIN_SH;
  for (int i = tid; i < BIN_NODES * 16; i += 512) {
    int n = nb + (i >> 4);
    if (n < N_NODES) agg[(size_t)n * H_F + g * 16 + (i & 15)] = acc[i] + bias;
  }
}

// ---------------- GEMM2: H2b = bf16(relu(agg1) @ W2) ----------------------
__global__ __launch_bounds__(256) void gemm2_kernel(
    const float* __restrict__ agg1, const float* __restrict__ W2,
    unsigned short* __restrict__ H2b) {
  __shared__ float w[H_F * C_F];
  for (int i = threadIdx.x; i < H_F * C_F; i += 256) w[i] = W2[i];
  __syncthreads();
  int idx = blockIdx.x * 256 + threadIdx.x;
  if (idx >= N_NODES * C_F) return;
  int n = idx >> 4;
  int f = idx & 15;
  const float* hr = agg1 + (size_t)n * H_F;
  float acc = 0.f;
#pragma unroll
  for (int k = 0; k < H_F; ++k) {
    float h = hr[k];
    h = h > 0.f ? h : 0.f;
    acc += h * w[k * C_F + f];
  }
  H2b[idx] = f2bf(acc);
}

// ---------------- Gather2 (binned, LDS accumulate, 2 halves/bin) ----------
__global__ __launch_bounds__(512) void gather2b_kernel(
    const unsigned short* __restrict__ H2b, const int* __restrict__ binOffs,
    const int2* __restrict__ ebin, float* __restrict__ part) {
  __shared__ float acc[BIN_NODES * 16];
  int b = blockIdx.x >> 1;
  int q = blockIdx.x & 1;
  int tid = threadIdx.x;
  for (int i = tid; i < BIN_NODES * 16; i += 512) acc[i] = 0.f;
  __syncthreads();
  int off0 = binOffs[b], end0 = binOffs[b + 1];
  int half = (end0 - off0 + 1) >> 1;
  int off = off0 + q * half;
  int end = (q == 0) ? (off0 + half) : end0;
  int sub = tid >> 4;
  int f = tid & 15;
  for (int ebase = off; ebase < end; ebase += 128) {
#pragma unroll
    for (int u = 0; u < 4; ++u) {
      int e = ebase + u * 32 + sub;
      int2 r = (e < end) ? ebin[e] : make_int2(0, 0);
      int srcn = r.x & 0x1FFFF;
      int dl = r.x >> 17;
      float w = __int_as_float(r.y);
      float v = bf2f(H2b[srcn * C_F + f]) * w;
      atomicAdd(&acc[dl * 16 + f], v);
    }
  }
  __syncthreads();
  int nb = b << BIN_SH;
  float* pq = part + (size_t)q * N_NODES * C_F;
  for (int i = tid; i < BIN_NODES * 16; i += 512) {
    int n = nb + (i >> 4);
    if (n < N_NODES) pq[(size_t)n * C_F + (i & 15)] = acc[i];
  }
}

__global__ __launch_bounds__(256) void merge2_kernel(
    const float* __restrict__ part, const float* __restrict__ b2,
    float* __restrict__ out) {
  int idx = blockIdx.x * 256 + threadIdx.x;
  if (idx < N_NODES * C_F)
    out[idx] = part[idx] + part[(size_t)N_NODES * C_F + idx] + b2[idx & 15];
}

extern "C" void kernel_launch(void* const* d_in, const int* in_sizes, int n_in,
                              void* d_out, int out_size, void* d_ws,
                              size_t ws_size, hipStream_t stream) {
  const float* X  = (const float*)d_in[0];
  const float* ew = (const float*)d_in[1];
  const float* W1 = (const float*)d_in[2];
  const float* b1 = (const float*)d_in[3];
  const float* W2 = (const float*)d_in[4];
  const float* b2 = (const float*)d_in[5];
  const int* src  = (const int*)d_in[6];
  const int* dst  = (const int*)d_in[7];
  float* out = (float*)d_out;

  // Workspace (~51.2 MB):
  //   H1b  bf16 [N x 64] 12.8 MB   (H2b bf16 [N x 16] aliases it after gather1)
  //   agg1 f32  [N x 64] 25.6 MB   (part f32 [2][N x 16] aliases after gemm2)
  //   ebin int2 [E]      12.8 MB
  //   binCnt/binOffs/binCursor     ~2.4 KB
  unsigned short* H1b = (unsigned short*)d_ws;
  float* agg1 = (float*)((char*)d_ws + (size_t)N_NODES * H_F * 2);
  int2* ebin  = (int2*)((char*)agg1 + (size_t)N_NODES * H_F * 4);
  int* binCnt = (int*)((char*)ebin + (size_t)N_EDGES * 8);
  int* binOffs = binCnt + NBINS;
  int* binCursor = binOffs + NBINS + 1;
  unsigned short* H2b = H1b;
  float* part = agg1;

  // bin build
  zero_bins_kernel<<<1, 256, 0, stream>>>(binCnt);
  bincount_kernel<<<CNT_BLOCKS, 256, 0, stream>>>(dst, binCnt);
  binscan_kernel<<<1, 256, 0, stream>>>(binCnt, binOffs, binCursor);
  partition_kernel<<<PART_BLOCKS, 256, 0, stream>>>(src, dst, ew, binCursor,
                                                    ebin);
  // layer 1
  gemm1_mfma_kernel<<<(N_NODES / 16 + 3) / 4, 256, 0, stream>>>(X, W1, H1b);
  gather1b_kernel<<<NBINS * 4, 512, 0, stream>>>(H1b, binOffs, ebin, b1, agg1);
  // layer 2
  gemm2_kernel<<<(N_NODES * C_F + 255) / 256, 256, 0, stream>>>(agg1, W2, H2b);
  gather2b_kernel<<<NBINS * 2, 512, 0, stream>>>(H2b, binOffs, ebin, part);
  merge2_kernel<<<(N_NODES * C_F + 255) / 256, 256, 0, stream>>>(part, b2, out);
}

// Round 6
// 293.644 us; speedup vs baseline: 3.5880x; 3.5880x over previous
//
#include <hip/hip_runtime.h>

#define N_NODES 100000
#define N_EDGES 1600000
#define IN_F 128
#define H_F 64
#define C_F 16

#define BIN_SH 9
#define BIN_NODES 512          // 1 << BIN_SH
#define NBINS 196              // ceil(100000 / 512)
#define PART_BLOCKS 192
#define CNT_BLOCKS 256

typedef __attribute__((ext_vector_type(8))) short bf16x8;  // 8 bf16 (4 VGPRs)
typedef __attribute__((ext_vector_type(4))) float f32x4;   // MFMA C/D

// fp32 -> bf16 round-to-nearest-even (finite inputs)
__device__ inline unsigned short f2bf(float f) {
  unsigned u = __float_as_uint(f);
  unsigned r = (u + 0x7fff + ((u >> 16) & 1)) >> 16;
  return (unsigned short)r;
}

// ---------------- GEMM1 (MFMA): H1b = bf16(X @ W1) ------------------------
// One wave = 16(node) x 64(feat) tile; B pre-swizzled in LDS (ds_read_b128).
__global__ __launch_bounds__(256) void gemm1_mfma_kernel(
    const float* __restrict__ X, const float* __restrict__ W1,
    unsigned short* __restrict__ H1b) {
  __shared__ short ldsB[16 * 512];  // 16 frags x (64 lanes x 8 bf16) = 16 KB
  for (int idx = threadIdx.x; idx < 16 * 512; idx += 256) {
    int frag = idx >> 9;    // c*4 + s
    int entry = idx & 511;  // lane*8 + j
    int lane = entry >> 3, j = entry & 7;
    int c = frag >> 2, s = frag & 3;
    int k = s * 32 + (lane >> 4) * 8 + j;
    int n = c * 16 + (lane & 15);
    ldsB[idx] = (short)f2bf(W1[k * H_F + n]);
  }
  __syncthreads();

  int wave = threadIdx.x >> 6;
  int lane = threadIdx.x & 63;
  int rt = blockIdx.x * 4 + wave;  // 16-node row tile
  if (rt >= N_NODES / 16) return;  // 6250 tiles exactly
  int node0 = rt * 16;
  int l = lane & 15, q = lane >> 4;

  const float* xp = X + (size_t)(node0 + l) * IN_F + q * 8;
  f32x4 acc[4] = {f32x4{0.f, 0.f, 0.f, 0.f}, f32x4{0.f, 0.f, 0.f, 0.f},
                  f32x4{0.f, 0.f, 0.f, 0.f}, f32x4{0.f, 0.f, 0.f, 0.f}};
#pragma unroll
  for (int s = 0; s < 4; ++s) {
    float4 x0 = *(const float4*)(xp + s * 32);
    float4 x1 = *(const float4*)(xp + s * 32 + 4);
    bf16x8 a;
    a[0] = f2bf(x0.x); a[1] = f2bf(x0.y); a[2] = f2bf(x0.z); a[3] = f2bf(x0.w);
    a[4] = f2bf(x1.x); a[5] = f2bf(x1.y); a[6] = f2bf(x1.z); a[7] = f2bf(x1.w);
#pragma unroll
    for (int c = 0; c < 4; ++c) {
      bf16x8 b = *(const bf16x8*)&ldsB[(c * 4 + s) * 512 + lane * 8];
      acc[c] = __builtin_amdgcn_mfma_f32_16x16x32_bf16(a, b, acc[c], 0, 0, 0);
    }
  }
  // C/D: col = lane&15 (feat), row = q*4 + reg (node)
#pragma unroll
  for (int c = 0; c < 4; ++c)
#pragma unroll
    for (int r = 0; r < 4; ++r)
      H1b[(size_t)(node0 + q * 4 + r) * H_F + c * 16 + l] = f2bf(acc[c][r]);
}

// ---------------- bin build: zero / count / scan / partition / binsort ----
__global__ __launch_bounds__(256) void zero_bins_kernel(int* __restrict__ binCnt) {
  if (threadIdx.x < NBINS) binCnt[threadIdx.x] = 0;
}

__global__ __launch_bounds__(256) void bincount_kernel(
    const int* __restrict__ dst, int* __restrict__ binCnt) {
  __shared__ int h[NBINS];
  int tid = threadIdx.x;
  if (tid < NBINS) h[tid] = 0;
  __syncthreads();
  for (int e = blockIdx.x * 256 + tid; e < N_EDGES; e += CNT_BLOCKS * 256)
    atomicAdd(&h[dst[e] >> BIN_SH], 1);
  __syncthreads();
  if (tid < NBINS) atomicAdd(&binCnt[tid], h[tid]);
}

__global__ __launch_bounds__(256) void binscan_kernel(
    const int* __restrict__ binCnt, int* __restrict__ binOffs,
    int* __restrict__ binCursor, int* __restrict__ offs) {
  __shared__ int s[256];
  int tid = threadIdx.x;
  int v = (tid < NBINS) ? binCnt[tid] : 0;
  s[tid] = v;
  __syncthreads();
#pragma unroll
  for (int d = 1; d < 256; d <<= 1) {
    int t = (tid >= d) ? s[tid - d] : 0;
    __syncthreads();
    s[tid] += t;
    __syncthreads();
  }
  if (tid < NBINS) {
    int ex = s[tid] - v;  // exclusive
    binOffs[tid] = ex;
    binCursor[tid] = ex;
  }
  if (tid == 0) {
    binOffs[NBINS] = N_EDGES;
    offs[N_NODES] = N_EDGES;  // CSR sentinel
  }
}

// Two-pass per-block partition into 196 dst-range bins. ~38K global atomics;
// stores land in per-(block,bin) contiguous runs -> L2-merged.
// Pack: x = src | (dst_local << 17), y = bits(weight).
__global__ __launch_bounds__(256) void partition_kernel(
    const int* __restrict__ src, const int* __restrict__ dst,
    const float* __restrict__ ew, int* __restrict__ binCursor,
    int2* __restrict__ ebin) {
  __shared__ int hist[NBINS];
  __shared__ int cur[NBINS];
  int tid = threadIdx.x;
  if (tid < NBINS) hist[tid] = 0;
  __syncthreads();
  const int per = (N_EDGES + PART_BLOCKS - 1) / PART_BLOCKS;
  int lo = blockIdx.x * per;
  int hi = lo + per;
  if (hi > N_EDGES) hi = N_EDGES;
  for (int e = lo + tid; e < hi; e += 256) atomicAdd(&hist[dst[e] >> BIN_SH], 1);
  __syncthreads();
  if (tid < NBINS) cur[tid] = atomicAdd(&binCursor[tid], hist[tid]);
  __syncthreads();
  for (int e = lo + tid; e < hi; e += 256) {
    int d = dst[e];
    int b = d >> BIN_SH;
    int pos = atomicAdd(&cur[b], 1);
    ebin[pos] = make_int2(src[e] | ((d & (BIN_NODES - 1)) << 17),
                          __float_as_int(ew[e]));
  }
}

// Per-bin LDS counting sort -> per-node CSR (offs + (src,w) records).
// All placement stores land in the bin's contiguous ~64KB window (L2-merged).
__global__ __launch_bounds__(512) void binsort_kernel(
    const int2* __restrict__ ebin, const int* __restrict__ binOffs,
    int2* __restrict__ epk, int* __restrict__ offs) {
  __shared__ int h[BIN_NODES];   // counts, later cursor
  __shared__ int s[BIN_NODES];   // scan workspace
  int b = blockIdx.x;
  int tid = threadIdx.x;
  int lo = binOffs[b], hi = binOffs[b + 1];
  h[tid] = 0;
  __syncthreads();
  for (int e = lo + tid; e < hi; e += 512)
    atomicAdd(&h[((unsigned)ebin[e].x) >> 17], 1);
  __syncthreads();
  int v = h[tid];
  s[tid] = v;
  __syncthreads();
#pragma unroll
  for (int d = 1; d < 512; d <<= 1) {
    int t = (tid >= d) ? s[tid - d] : 0;
    __syncthreads();
    s[tid] += t;
    __syncthreads();
  }
  int ex = lo + s[tid] - v;  // global exclusive offset for local node tid
  int n = (b << BIN_SH) + tid;
  if (n < N_NODES) offs[n] = ex;
  h[tid] = ex;  // cursor
  __syncthreads();
  for (int e = lo + tid; e < hi; e += 512) {
    int2 r = ebin[e];
    int dl = ((unsigned)r.x) >> 17;
    int pos = atomicAdd(&h[dl], 1);
    epk[pos] = make_int2(r.x & 0x1FFFF, r.y);
  }
}

// ---------------- Gather1: agg[n,:] = b1 + sum_in w_e * H1b[src,:] --------
// Wave per node. 2 bf16 feats/lane (uint), 2 edge-halves (h=lane>>5),
// unroll x2 -> 4 edges in flight. shfl_xor(32) combine, half-wave writes f32.
__global__ __launch_bounds__(256) void gather1_kernel(
    const unsigned short* __restrict__ H1b, const int* __restrict__ offs,
    const int2* __restrict__ epk, const float* __restrict__ b1,
    float* __restrict__ agg) {
  int t = blockIdx.x * 256 + threadIdx.x;
  int n = t >> 6;
  if (n >= N_NODES) return;
  int lane = t & 63;
  int h = lane >> 5, li = lane & 31;
  int beg = offs[n], end = offs[n + 1];
  const unsigned* H1u = (const unsigned*)H1b;
  float ax0 = 0.f, ay0 = 0.f, ax1 = 0.f, ay1 = 0.f;
  int i = beg;
  for (; i + 3 < end; i += 4) {
    int2 r0 = epk[i + h];
    int2 r1 = epk[i + 2 + h];
    float w0 = __int_as_float(r0.y), w1 = __int_as_float(r1.y);
    unsigned v0 = H1u[r0.x * (H_F / 2) + li];
    unsigned v1 = H1u[r1.x * (H_F / 2) + li];
    ax0 += __uint_as_float(v0 << 16) * w0;
    ay0 += __uint_as_float(v0 & 0xFFFF0000u) * w0;
    ax1 += __uint_as_float(v1 << 16) * w1;
    ay1 += __uint_as_float(v1 & 0xFFFF0000u) * w1;
  }
  for (; i + h < end; i += 2) {
    int2 r0 = epk[i + h];
    float w0 = __int_as_float(r0.y);
    unsigned v0 = H1u[r0.x * (H_F / 2) + li];
    ax0 += __uint_as_float(v0 << 16) * w0;
    ay0 += __uint_as_float(v0 & 0xFFFF0000u) * w0;
  }
  float ax = ax0 + ax1, ay = ay0 + ay1;
  ax += __shfl_xor(ax, 32, 64);
  ay += __shfl_xor(ay, 32, 64);
  if (h == 0) {
    float2 o;
    o.x = ax + b1[li * 2];
    o.y = ay + b1[li * 2 + 1];
    *(float2*)&agg[(size_t)n * H_F + li * 2] = o;
  }
}

// ---------------- GEMM2 (MFMA): H2b = bf16(relu(agg) @ W2) ----------------
// One wave = 16 nodes x 16 cols, K=64 (2 k-steps). relu fused on A read.
__global__ __launch_bounds__(256) void gemm2_mfma_kernel(
    const float* __restrict__ agg, const float* __restrict__ W2,
    unsigned short* __restrict__ H2b) {
  __shared__ short ldsB[2 * 512];  // 2 k-frags x (64 lanes x 8 bf16) = 2 KB
  for (int idx = threadIdx.x; idx < 1024; idx += 256) {
    int sfrag = idx >> 9;
    int entry = idx & 511;
    int lane = entry >> 3, j = entry & 7;
    int k = sfrag * 32 + (lane >> 4) * 8 + j;
    int c = lane & 15;
    ldsB[idx] = (short)f2bf(W2[k * C_F + c]);
  }
  __syncthreads();
  int wave = threadIdx.x >> 6;
  int lane = threadIdx.x & 63;
  int rt = blockIdx.x * 4 + wave;
  if (rt >= N_NODES / 16) return;  // 6250 exactly
  int node0 = rt * 16;
  int l = lane & 15, q = lane >> 4;
  const float* ap = agg + (size_t)(node0 + l) * H_F + q * 8;
  f32x4 acc = {0.f, 0.f, 0.f, 0.f};
#pragma unroll
  for (int s = 0; s < 2; ++s) {
    float4 x0 = *(const float4*)(ap + s * 32);
    float4 x1 = *(const float4*)(ap + s * 32 + 4);
    bf16x8 a;
    a[0] = f2bf(fmaxf(x0.x, 0.f)); a[1] = f2bf(fmaxf(x0.y, 0.f));
    a[2] = f2bf(fmaxf(x0.z, 0.f)); a[3] = f2bf(fmaxf(x0.w, 0.f));
    a[4] = f2bf(fmaxf(x1.x, 0.f)); a[5] = f2bf(fmaxf(x1.y, 0.f));
    a[6] = f2bf(fmaxf(x1.z, 0.f)); a[7] = f2bf(fmaxf(x1.w, 0.f));
    bf16x8 bfr = *(const bf16x8*)&ldsB[s * 512 + lane * 8];
    acc = __builtin_amdgcn_mfma_f32_16x16x32_bf16(a, bfr, acc, 0, 0, 0);
  }
#pragma unroll
  for (int r = 0; r < 4; ++r)
    H2b[(size_t)(node0 + q * 4 + r) * C_F + l] = f2bf(acc[r]);
}

// ---------------- Gather2: out[n,:] = b2 + sum_in w_e * H2b[src,:] --------
// Wave per node: 2 bf16 feats/lane (8 uints/row), 8 edge-groups (h=lane>>3).
// H2b is 3.2 MB -> L2-resident. 3-step shfl_xor combine, 8 lanes write f32.
__global__ __launch_bounds__(256) void gather2_kernel(
    const unsigned short* __restrict__ H2b, const int* __restrict__ offs,
    const int2* __restrict__ epk, const float* __restrict__ b2,
    float* __restrict__ out) {
  int t = blockIdx.x * 256 + threadIdx.x;
  int n = t >> 6;
  if (n >= N_NODES) return;
  int lane = t & 63;
  int h = lane >> 3, li = lane & 7;
  int beg = offs[n], end = offs[n + 1];
  const unsigned* H2u = (const unsigned*)H2b;
  float ax = 0.f, ay = 0.f;
  for (int i = beg; i + h < end; i += 8) {
    int2 r = epk[i + h];
    float w = __int_as_float(r.y);
    unsigned v = H2u[r.x * (C_F / 2) + li];
    ax += __uint_as_float(v << 16) * w;
    ay += __uint_as_float(v & 0xFFFF0000u) * w;
  }
#pragma unroll
  for (int m = 8; m < 64; m <<= 1) {
    ax += __shfl_xor(ax, m, 64);
    ay += __shfl_xor(ay, m, 64);
  }
  if (h == 0) {
    float2 o;
    o.x = ax + b2[li * 2];
    o.y = ay + b2[li * 2 + 1];
    *(float2*)&out[(size_t)n * C_F + li * 2] = o;
  }
}

extern "C" void kernel_launch(void* const* d_in, const int* in_sizes, int n_in,
                              void* d_out, int out_size, void* d_ws,
                              size_t ws_size, hipStream_t stream) {
  const float* X  = (const float*)d_in[0];
  const float* ew = (const float*)d_in[1];
  const float* W1 = (const float*)d_in[2];
  const float* b1 = (const float*)d_in[3];
  const float* W2 = (const float*)d_in[4];
  const float* b2 = (const float*)d_in[5];
  const int* src  = (const int*)d_in[6];
  const int* dst  = (const int*)d_in[7];
  float* out = (float*)d_out;

  // Workspace (~64.4 MB):
  //   H1b bf16 [N x 64] 12.8 MB (H2b bf16 [N x 16] aliases it)
  //   agg f32  [N x 64] 25.6 MB
  //   ebin int2 [E]     12.8 MB (bin-sorted, dl-packed)
  //   epk  int2 [E]     12.8 MB (node-sorted CSR records)
  //   offs int [N+1], binCnt/binOffs/binCursor
  unsigned short* H1b = (unsigned short*)d_ws;
  float* agg  = (float*)((char*)d_ws + (size_t)N_NODES * H_F * 2);
  int2* ebin  = (int2*)((char*)agg + (size_t)N_NODES * H_F * 4);
  int2* epk   = ebin + N_EDGES;
  int* offs   = (int*)(epk + N_EDGES);
  int* binCnt = offs + N_NODES + 32;
  int* binOffs = binCnt + NBINS;
  int* binCursor = binOffs + NBINS + 1;
  unsigned short* H2b = H1b;

  // build per-node CSR via bin partition + per-bin LDS counting sort
  zero_bins_kernel<<<1, 256, 0, stream>>>(binCnt);
  bincount_kernel<<<CNT_BLOCKS, 256, 0, stream>>>(dst, binCnt);
  binscan_kernel<<<1, 256, 0, stream>>>(binCnt, binOffs, binCursor, offs);
  partition_kernel<<<PART_BLOCKS, 256, 0, stream>>>(src, dst, ew, binCursor,
                                                    ebin);
  binsort_kernel<<<NBINS, 512, 0, stream>>>(ebin, binOffs, epk, offs);
  // layer 1
  gemm1_mfma_kernel<<<(N_NODES / 16 + 3) / 4, 256, 0, stream>>>(X, W1, H1b);
  gather1_kernel<<<(N_NODES * 64 + 255) / 256, 256, 0, stream>>>(H1b, offs,
                                                                 epk, b1, agg);
  // layer 2
  gemm2_mfma_kernel<<<(N_NODES / 16 + 3) / 4, 256, 0, stream>>>(agg, W2, H2b);
  gather2_kernel<<<(N_NODES * 64 + 255) / 256, 256, 0, stream>>>(H2b, offs,
                                                                 epk, b2, out);
}

// Round 7
// 281.464 us; speedup vs baseline: 3.7432x; 1.0433x over previous
//
#include <hip/hip_runtime.h>

#define N_NODES 100000
#define N_EDGES 1600000
#define IN_F 128
#define H_F 64
#define C_F 16

#define BIN_SH 8
#define BIN_NODES 256          // 1 << BIN_SH
#define NBINS 391              // ceil(100000 / 256)
#define PART_BLOCKS 192
#define CNT_BLOCKS 256
#define BSORT_MAX 24           // max edges/thread in binsort (6144/bin >> 4.3K tail)

typedef __attribute__((ext_vector_type(8))) short bf16x8;  // 8 bf16 (4 VGPRs)
typedef __attribute__((ext_vector_type(4))) float f32x4;   // MFMA C/D

// fp32 -> bf16 round-to-nearest-even (finite inputs)
__device__ inline unsigned short f2bf(float f) {
  unsigned u = __float_as_uint(f);
  unsigned r = (u + 0x7fff + ((u >> 16) & 1)) >> 16;
  return (unsigned short)r;
}

// ---------------- GEMM1 (MFMA): H1b = bf16(X @ W1) ------------------------
// One wave = 16(node) x 64(feat) tile; B pre-swizzled in LDS (ds_read_b128).
__global__ __launch_bounds__(256) void gemm1_mfma_kernel(
    const float* __restrict__ X, const float* __restrict__ W1,
    unsigned short* __restrict__ H1b) {
  __shared__ short ldsB[16 * 512];  // 16 frags x (64 lanes x 8 bf16) = 16 KB
  for (int idx = threadIdx.x; idx < 16 * 512; idx += 256) {
    int frag = idx >> 9;    // c*4 + s
    int entry = idx & 511;  // lane*8 + j
    int lane = entry >> 3, j = entry & 7;
    int c = frag >> 2, s = frag & 3;
    int k = s * 32 + (lane >> 4) * 8 + j;
    int n = c * 16 + (lane & 15);
    ldsB[idx] = (short)f2bf(W1[k * H_F + n]);
  }
  __syncthreads();

  int wave = threadIdx.x >> 6;
  int lane = threadIdx.x & 63;
  int rt = blockIdx.x * 4 + wave;  // 16-node row tile
  if (rt >= N_NODES / 16) return;  // 6250 tiles exactly
  int node0 = rt * 16;
  int l = lane & 15, q = lane >> 4;

  const float* xp = X + (size_t)(node0 + l) * IN_F + q * 8;
  f32x4 acc[4] = {f32x4{0.f, 0.f, 0.f, 0.f}, f32x4{0.f, 0.f, 0.f, 0.f},
                  f32x4{0.f, 0.f, 0.f, 0.f}, f32x4{0.f, 0.f, 0.f, 0.f}};
#pragma unroll
  for (int s = 0; s < 4; ++s) {
    float4 x0 = *(const float4*)(xp + s * 32);
    float4 x1 = *(const float4*)(xp + s * 32 + 4);
    bf16x8 a;
    a[0] = f2bf(x0.x); a[1] = f2bf(x0.y); a[2] = f2bf(x0.z); a[3] = f2bf(x0.w);
    a[4] = f2bf(x1.x); a[5] = f2bf(x1.y); a[6] = f2bf(x1.z); a[7] = f2bf(x1.w);
#pragma unroll
    for (int c = 0; c < 4; ++c) {
      bf16x8 b = *(const bf16x8*)&ldsB[(c * 4 + s) * 512 + lane * 8];
      acc[c] = __builtin_amdgcn_mfma_f32_16x16x32_bf16(a, b, acc[c], 0, 0, 0);
    }
  }
  // C/D: col = lane&15 (feat), row = q*4 + reg (node)
#pragma unroll
  for (int c = 0; c < 4; ++c)
#pragma unroll
    for (int r = 0; r < 4; ++r)
      H1b[(size_t)(node0 + q * 4 + r) * H_F + c * 16 + l] = f2bf(acc[c][r]);
}

// ---------------- bin build: zero / count / scan / partition / binsort ----
__global__ __launch_bounds__(512) void zero_bins_kernel(int* __restrict__ binCnt) {
  if (threadIdx.x < NBINS) binCnt[threadIdx.x] = 0;
}

__global__ __launch_bounds__(256) void bincount_kernel(
    const int* __restrict__ dst, int* __restrict__ binCnt) {
  __shared__ int h[NBINS];
  int tid = threadIdx.x;
  for (int i = tid; i < NBINS; i += 256) h[i] = 0;
  __syncthreads();
  for (int e = blockIdx.x * 256 + tid; e < N_EDGES; e += CNT_BLOCKS * 256)
    atomicAdd(&h[dst[e] >> BIN_SH], 1);
  __syncthreads();
  for (int i = tid; i < NBINS; i += 256)
    if (h[i]) atomicAdd(&binCnt[i], h[i]);
}

__global__ __launch_bounds__(512) void binscan_kernel(
    const int* __restrict__ binCnt, int* __restrict__ binOffs,
    int* __restrict__ binCursor, int* __restrict__ offs) {
  __shared__ int s[512];
  int tid = threadIdx.x;
  int v = (tid < NBINS) ? binCnt[tid] : 0;
  s[tid] = v;
  __syncthreads();
#pragma unroll
  for (int d = 1; d < 512; d <<= 1) {
    int t = (tid >= d) ? s[tid - d] : 0;
    __syncthreads();
    s[tid] += t;
    __syncthreads();
  }
  if (tid < NBINS) {
    int ex = s[tid] - v;  // exclusive
    binOffs[tid] = ex;
    binCursor[tid] = ex;
  }
  if (tid == 0) {
    binOffs[NBINS] = N_EDGES;
    offs[N_NODES] = N_EDGES;  // CSR sentinel
  }
}

// Two-pass per-block partition into 391 dst-range bins. ~75K global atomics;
// stores land in per-(block,bin) contiguous runs -> L2-merged.
// Pack: x = src | (dst_local << 17), y = bits(weight).
__global__ __launch_bounds__(256) void partition_kernel(
    const int* __restrict__ src, const int* __restrict__ dst,
    const float* __restrict__ ew, int* __restrict__ binCursor,
    int2* __restrict__ ebin) {
  __shared__ int hist[NBINS];
  __shared__ int cur[NBINS];
  int tid = threadIdx.x;
  for (int i = tid; i < NBINS; i += 256) hist[i] = 0;
  __syncthreads();
  const int per = (N_EDGES + PART_BLOCKS - 1) / PART_BLOCKS;
  int lo = blockIdx.x * per;
  int hi = lo + per;
  if (hi > N_EDGES) hi = N_EDGES;
  for (int e = lo + tid; e < hi; e += 256) atomicAdd(&hist[dst[e] >> BIN_SH], 1);
  __syncthreads();
  for (int i = tid; i < NBINS; i += 256)
    cur[i] = hist[i] ? atomicAdd(&binCursor[i], hist[i]) : 0;
  __syncthreads();
  for (int e = lo + tid; e < hi; e += 256) {
    int d = dst[e];
    int b = d >> BIN_SH;
    int pos = atomicAdd(&cur[b], 1);
    ebin[pos] = make_int2(src[e] | ((d & (BIN_NODES - 1)) << 17),
                          __float_as_int(ew[e]));
  }
}

// Per-bin LDS counting sort -> per-node CSR. Single global read of ebin:
// records cached in registers between count and placement passes.
__global__ __launch_bounds__(256) void binsort_kernel(
    const int2* __restrict__ ebin, const int* __restrict__ binOffs,
    int2* __restrict__ epk, int* __restrict__ offs) {
  __shared__ int h[BIN_NODES];   // counts, later cursor
  __shared__ int s[BIN_NODES];   // scan workspace
  int b = blockIdx.x;
  int tid = threadIdx.x;
  int lo = binOffs[b], hi = binOffs[b + 1];
  h[tid] = 0;
  __syncthreads();
  int2 r[BSORT_MAX];
  int cnt = 0;
#pragma unroll
  for (int j = 0; j < BSORT_MAX; ++j) {
    int e = lo + j * 256 + tid;
    if (e < hi) {
      r[j] = ebin[e];
      atomicAdd(&h[((unsigned)r[j].x) >> 17], 1);
      cnt = j + 1;
    }
  }
  __syncthreads();
  int v = h[tid];
  s[tid] = v;
  __syncthreads();
#pragma unroll
  for (int d = 1; d < 256; d <<= 1) {
    int t = (tid >= d) ? s[tid - d] : 0;
    __syncthreads();
    s[tid] += t;
    __syncthreads();
  }
  int ex = lo + s[tid] - v;  // global exclusive offset for local node tid
  int n = (b << BIN_SH) + tid;
  if (n < N_NODES) offs[n] = ex;
  h[tid] = ex;  // cursor
  __syncthreads();
#pragma unroll
  for (int j = 0; j < BSORT_MAX; ++j) {
    if (j < cnt) {
      int dl = ((unsigned)r[j].x) >> 17;
      int pos = atomicAdd(&h[dl], 1);
      epk[pos] = make_int2(r[j].x & 0x1FFFF, r[j].y);
    }
  }
}

// ---------------- Gather1: agg[n,:] = b1 + sum_in w_e * H1b[src,:] --------
// Wave per node. 2 bf16 feats/lane, 2 edge-halves (h=lane>>5), unroll x4
// -> 8 edges in flight. shfl_xor(32) combine, half-wave writes f32.
__global__ __launch_bounds__(256) void gather1_kernel(
    const unsigned short* __restrict__ H1b, const int* __restrict__ offs,
    const int2* __restrict__ epk, const float* __restrict__ b1,
    float* __restrict__ agg) {
  int t = blockIdx.x * 256 + threadIdx.x;
  int n = t >> 6;
  if (n >= N_NODES) return;
  int lane = t & 63;
  int h = lane >> 5, li = lane & 31;
  int beg = offs[n], end = offs[n + 1];
  const unsigned* H1u = (const unsigned*)H1b;
  float ax0 = 0.f, ay0 = 0.f, ax1 = 0.f, ay1 = 0.f;
  float ax2 = 0.f, ay2 = 0.f, ax3 = 0.f, ay3 = 0.f;
  int i = beg;
  for (; i + 7 < end; i += 8) {
    int2 r0 = epk[i + h];
    int2 r1 = epk[i + 2 + h];
    int2 r2 = epk[i + 4 + h];
    int2 r3 = epk[i + 6 + h];
    unsigned v0 = H1u[r0.x * (H_F / 2) + li];
    unsigned v1 = H1u[r1.x * (H_F / 2) + li];
    unsigned v2 = H1u[r2.x * (H_F / 2) + li];
    unsigned v3 = H1u[r3.x * (H_F / 2) + li];
    float w0 = __int_as_float(r0.y), w1 = __int_as_float(r1.y);
    float w2 = __int_as_float(r2.y), w3 = __int_as_float(r3.y);
    ax0 += __uint_as_float(v0 << 16) * w0;
    ay0 += __uint_as_float(v0 & 0xFFFF0000u) * w0;
    ax1 += __uint_as_float(v1 << 16) * w1;
    ay1 += __uint_as_float(v1 & 0xFFFF0000u) * w1;
    ax2 += __uint_as_float(v2 << 16) * w2;
    ay2 += __uint_as_float(v2 & 0xFFFF0000u) * w2;
    ax3 += __uint_as_float(v3 << 16) * w3;
    ay3 += __uint_as_float(v3 & 0xFFFF0000u) * w3;
  }
  for (; i + 3 < end; i += 4) {
    int2 r0 = epk[i + h];
    int2 r1 = epk[i + 2 + h];
    unsigned v0 = H1u[r0.x * (H_F / 2) + li];
    unsigned v1 = H1u[r1.x * (H_F / 2) + li];
    float w0 = __int_as_float(r0.y), w1 = __int_as_float(r1.y);
    ax0 += __uint_as_float(v0 << 16) * w0;
    ay0 += __uint_as_float(v0 & 0xFFFF0000u) * w0;
    ax1 += __uint_as_float(v1 << 16) * w1;
    ay1 += __uint_as_float(v1 & 0xFFFF0000u) * w1;
  }
  for (; i + h < end; i += 2) {
    int2 r0 = epk[i + h];
    float w0 = __int_as_float(r0.y);
    unsigned v0 = H1u[r0.x * (H_F / 2) + li];
    ax0 += __uint_as_float(v0 << 16) * w0;
    ay0 += __uint_as_float(v0 & 0xFFFF0000u) * w0;
  }
  float ax = (ax0 + ax1) + (ax2 + ax3);
  float ay = (ay0 + ay1) + (ay2 + ay3);
  ax += __shfl_xor(ax, 32, 64);
  ay += __shfl_xor(ay, 32, 64);
  if (h == 0) {
    float2 o;
    o.x = ax + b1[li * 2];
    o.y = ay + b1[li * 2 + 1];
    *(float2*)&agg[(size_t)n * H_F + li * 2] = o;
  }
}

// ---------------- GEMM2 (MFMA): H2b = bf16(relu(agg) @ W2) ----------------
// One wave = 16 nodes x 16 cols, K=64 (2 k-steps). relu fused on A read.
__global__ __launch_bounds__(256) void gemm2_mfma_kernel(
    const float* __restrict__ agg, const float* __restrict__ W2,
    unsigned short* __restrict__ H2b) {
  __shared__ short ldsB[2 * 512];  // 2 k-frags x (64 lanes x 8 bf16) = 2 KB
  for (int idx = threadIdx.x; idx < 1024; idx += 256) {
    int sfrag = idx >> 9;
    int entry = idx & 511;
    int lane = entry >> 3, j = entry & 7;
    int k = sfrag * 32 + (lane >> 4) * 8 + j;
    int c = lane & 15;
    ldsB[idx] = (short)f2bf(W2[k * C_F + c]);
  }
  __syncthreads();
  int wave = threadIdx.x >> 6;
  int lane = threadIdx.x & 63;
  int rt = blockIdx.x * 4 + wave;
  if (rt >= N_NODES / 16) return;  // 6250 exactly
  int node0 = rt * 16;
  int l = lane & 15, q = lane >> 4;
  const float* ap = agg + (size_t)(node0 + l) * H_F + q * 8;
  f32x4 acc = {0.f, 0.f, 0.f, 0.f};
#pragma unroll
  for (int s = 0; s < 2; ++s) {
    float4 x0 = *(const float4*)(ap + s * 32);
    float4 x1 = *(const float4*)(ap + s * 32 + 4);
    bf16x8 a;
    a[0] = f2bf(fmaxf(x0.x, 0.f)); a[1] = f2bf(fmaxf(x0.y, 0.f));
    a[2] = f2bf(fmaxf(x0.z, 0.f)); a[3] = f2bf(fmaxf(x0.w, 0.f));
    a[4] = f2bf(fmaxf(x1.x, 0.f)); a[5] = f2bf(fmaxf(x1.y, 0.f));
    a[6] = f2bf(fmaxf(x1.z, 0.f)); a[7] = f2bf(fmaxf(x1.w, 0.f));
    bf16x8 bfr = *(const bf16x8*)&ldsB[s * 512 + lane * 8];
    acc = __builtin_amdgcn_mfma_f32_16x16x32_bf16(a, bfr, acc, 0, 0, 0);
  }
#pragma unroll
  for (int r = 0; r < 4; ++r)
    H2b[(size_t)(node0 + q * 4 + r) * C_F + l] = f2bf(acc[r]);
}

// ---------------- Gather2: out[n,:] = b2 + sum_in w_e * H2b[src,:] --------
// Wave per node: 2 bf16 feats/lane, 8 edge-groups (h=lane>>3), unroll x2
// -> 16 edges in flight. H2b is 3.2 MB -> L2-resident.
__global__ __launch_bounds__(256) void gather2_kernel(
    const unsigned short* __restrict__ H2b, const int* __restrict__ offs,
    const int2* __restrict__ epk, const float* __restrict__ b2,
    float* __restrict__ out) {
  int t = blockIdx.x * 256 + threadIdx.x;
  int n = t >> 6;
  if (n >= N_NODES) return;
  int lane = t & 63;
  int h = lane >> 3, li = lane & 7;
  int beg = offs[n], end = offs[n + 1];
  const unsigned* H2u = (const unsigned*)H2b;
  float ax0 = 0.f, ay0 = 0.f, ax1 = 0.f, ay1 = 0.f;
  int i = beg;
  for (; i + 15 < end; i += 16) {
    int2 r0 = epk[i + h];
    int2 r1 = epk[i + 8 + h];
    unsigned v0 = H2u[r0.x * (C_F / 2) + li];
    unsigned v1 = H2u[r1.x * (C_F / 2) + li];
    float w0 = __int_as_float(r0.y), w1 = __int_as_float(r1.y);
    ax0 += __uint_as_float(v0 << 16) * w0;
    ay0 += __uint_as_float(v0 & 0xFFFF0000u) * w0;
    ax1 += __uint_as_float(v1 << 16) * w1;
    ay1 += __uint_as_float(v1 & 0xFFFF0000u) * w1;
  }
  for (; i + h < end; i += 8) {
    int2 r = epk[i + h];
    float w = __int_as_float(r.y);
    unsigned v = H2u[r.x * (C_F / 2) + li];
    ax0 += __uint_as_float(v << 16) * w;
    ay0 += __uint_as_float(v & 0xFFFF0000u) * w;
  }
  float ax = ax0 + ax1, ay = ay0 + ay1;
#pragma unroll
  for (int m = 8; m < 64; m <<= 1) {
    ax += __shfl_xor(ax, m, 64);
    ay += __shfl_xor(ay, m, 64);
  }
  if (h == 0) {
    float2 o;
    o.x = ax + b2[li * 2];
    o.y = ay + b2[li * 2 + 1];
    *(float2*)&out[(size_t)n * C_F + li * 2] = o;
  }
}

extern "C" void kernel_launch(void* const* d_in, const int* in_sizes, int n_in,
                              void* d_out, int out_size, void* d_ws,
                              size_t ws_size, hipStream_t stream) {
  const float* X  = (const float*)d_in[0];
  const float* ew = (const float*)d_in[1];
  const float* W1 = (const float*)d_in[2];
  const float* b1 = (const float*)d_in[3];
  const float* W2 = (const float*)d_in[4];
  const float* b2 = (const float*)d_in[5];
  const int* src  = (const int*)d_in[6];
  const int* dst  = (const int*)d_in[7];
  float* out = (float*)d_out;

  // Workspace (~64.8 MB):
  //   H1b bf16 [N x 64] 12.8 MB (H2b bf16 [N x 16] aliases it)
  //   agg f32  [N x 64] 25.6 MB
  //   ebin int2 [E]     12.8 MB (bin-partitioned, dl-packed)
  //   epk  int2 [E]     12.8 MB (node-sorted CSR records)
  //   offs int [N+1], binCnt/binOffs/binCursor
  unsigned short* H1b = (unsigned short*)d_ws;
  float* agg  = (float*)((char*)d_ws + (size_t)N_NODES * H_F * 2);
  int2* ebin  = (int2*)((char*)agg + (size_t)N_NODES * H_F * 4);
  int2* epk   = ebin + N_EDGES;
  int* offs   = (int*)(epk + N_EDGES);
  int* binCnt = offs + N_NODES + 32;
  int* binOffs = binCnt + NBINS;
  int* binCursor = binOffs + NBINS + 1;
  unsigned short* H2b = H1b;

  // build per-node CSR via bin partition + per-bin LDS counting sort
  zero_bins_kernel<<<1, 512, 0, stream>>>(binCnt);
  bincount_kernel<<<CNT_BLOCKS, 256, 0, stream>>>(dst, binCnt);
  binscan_kernel<<<1, 512, 0, stream>>>(binCnt, binOffs, binCursor, offs);
  partition_kernel<<<PART_BLOCKS, 256, 0, stream>>>(src, dst, ew, binCursor,
                                                    ebin);
  binsort_kernel<<<NBINS, 256, 0, stream>>>(ebin, binOffs, epk, offs);
  // layer 1
  gemm1_mfma_kernel<<<(N_NODES / 16 + 3) / 4, 256, 0, stream>>>(X, W1, H1b);
  gather1_kernel<<<(N_NODES * 64 + 255) / 256, 256, 0, stream>>>(H1b, offs,
                                                                 epk, b1, agg);
  // layer 2
  gemm2_mfma_kernel<<<(N_NODES / 16 + 3) / 4, 256, 0, stream>>>(agg, W2, H2b);
  gather2_kernel<<<(N_NODES * 64 + 255) / 256, 256, 0, stream>>>(H2b, offs,
                                                                 epk, b2, out);
}